// Round 20
// baseline (592.715 us; speedup 1.0000x reference)
//
#include <hip/hip_runtime.h>
#include <math.h>

typedef _Float16 half8 __attribute__((ext_vector_type(8)));
typedef _Float16 half4 __attribute__((ext_vector_type(4)));
typedef float f32x16 __attribute__((ext_vector_type(16)));

// ---------------------------------------------------------------------------
// xprep: split x (f32) into global f16 hi/lo planes (one-shot).
// ---------------------------------------------------------------------------
__global__ __launch_bounds__(256) void xprep_k(const float* __restrict__ x,
                                               _Float16* __restrict__ xh,
                                               _Float16* __restrict__ xl) {
  const int i = blockIdx.x * 256 + threadIdx.x;  // x4 floats
  if (i >= 2097152) return;
  const float4 v = *(const float4*)(x + (size_t)i * 4);
  half4 h, l;
  const float vv[4] = {v.x, v.y, v.z, v.w};
#pragma unroll
  for (int e = 0; e < 4; ++e) {
    const _Float16 hh = (_Float16)vv[e];
    h[e] = hh;
    l[e] = (_Float16)((vv[e] - (float)hh) * 1024.0f);
  }
  *(half4*)(xh + (size_t)i * 4) = h;
  *(half4*)(xl + (size_t)i * 4) = l;
}

// ---------------------------------------------------------------------------
// w1prep: conv1-MFMA B-fragment order, split hi/lo, K padded 25->32.
// ---------------------------------------------------------------------------
__global__ __launch_bounds__(256) void w1prep_k(const float* __restrict__ w1,
                                                _Float16* __restrict__ w1p) {
  const int i = blockIdx.x * 256 + threadIdx.x;
  if (i >= 1024) return;
  const int blk = i >> 8;
  const int s = blk >> 1, g = blk & 1;
  const int ch = (i >> 3) & 31, e = i & 7;
  const int k = s * 16 + g * 8 + e;
  float v = 0.f;
  if (k < 25) v = w1[ch * 25 + k];
  const _Float16 h = (_Float16)v;
  w1p[i] = h;
  w1p[1024 + i] = (_Float16)((v - (float)h) * 1024.0f);
}

// ---------------------------------------------------------------------------
// w2prep: pack w2 into MFMA-fragment order, split hi/lo f16.
// ---------------------------------------------------------------------------
__global__ __launch_bounds__(256) void w2prep_k(const float* __restrict__ w2,
                                                _Float16* __restrict__ w2p) {
  const int i = blockIdx.x * 256 + threadIdx.x;
  if (i >= 18432) return;
  const int tap = i >> 11;
  const int r = i & 2047;
  const int blk = r >> 8;
  const int nt = blk >> 2, s = (blk >> 1) & 1, g = blk & 1;
  const int n = (r >> 3) & 31, e = r & 7;
  const int och = nt * 32 + n;
  const int ic = s * 16 + g * 8 + e;
  const float v = w2[och * 288 + ic * 9 + tap];
  const _Float16 h = (_Float16)v;
  const _Float16 l = (_Float16)((v - (float)h) * 1024.0f);
  w2p[i] = h;
  w2p[18432 + i] = l;
}

// ---------------------------------------------------------------------------
// w3prep: pack w3 into conv3's fragment-order image.
// ---------------------------------------------------------------------------
__global__ __launch_bounds__(256) void w3prep_k(const float* __restrict__ w3,
                                                _Float16* __restrict__ w3p) {
  const int i = blockIdx.x * 256 + threadIdx.x;
  if (i >= 55296) return;
  const int icc = i / 27648;
  const int r1 = i - icc * 27648;
  const int tc = r1 / 6144;
  const int rem = r1 - tc * 6144;
  const int tl = rem / 3072;
  const int rem2 = rem - tl * 3072;
  const int nt = rem2 >> 10;
  const int s = (rem2 >> 9) & 1;
  const int g = (rem2 >> 8) & 1;
  const int n = (rem2 >> 3) & 31;
  const int e = rem2 & 7;
  const int tap = tc * 2 + tl;
  const int och = nt * 32 + n;
  const int ic = icc * 32 + s * 16 + g * 8 + e;
  const float v = w3[(size_t)och * 576 + ic * 9 + tap];
  const _Float16 h = (_Float16)v;
  const _Float16 l = (_Float16)((v - (float)h) * 1024.0f);
  w3p[i] = h;
  w3p[55296 + i] = l;
}

// ---------------------------------------------------------------------------
// winprep: pack w_in into ff-GEMM B-fragment order, split f16.
// ---------------------------------------------------------------------------
__global__ __launch_bounds__(256) void winprep_k(const float* __restrict__ w_in,
                                                 _Float16* __restrict__ winp) {
  const int i = blockIdx.x * 256 + threadIdx.x;
  if (i >= 1769472) return;
  const int ks = i >> 11;
  const int rem = i & 2047;
  const int nt = rem >> 9;
  const int g = (rem >> 8) & 1;
  const int n = (rem >> 3) & 31;
  const int e = rem & 7;
  const int h = nt * 32 + n;
  const int k = ks * 16 + g * 8 + e;
  const float v = w_in[(size_t)h * 13824 + k];
  const _Float16 hh = (_Float16)v;
  const _Float16 ll = (_Float16)((v - (float)hh) * 1024.0f);
  winp[i] = hh;
  winp[1769472 + i] = ll;
}

// ---------------------------------------------------------------------------
// conv2f v7: FUSED conv1(MFMA) + conv2(MFMA) + maxpool.
// Phase 2 B-operands staged per-tc in LDS (7-way cross-wave reuse; R13's
// verified staging/read algebra) -- removes the ~516 KB/block L1/L2 B-read
// traffic that capped MfmaUtil at 30%.
// LDS S[31232] hw (62,464 B): Xh[0,11520) Xl[11520,23040);
//   strips hi@23040 lo@24000 (phase 1, dead after);
//   W per-tc: Wh@23040 (4096 hw) Wl@27136 (4096 hw);
//   pool overlay f32 [112][68] per-img halves.
// ---------------------------------------------------------------------------
__global__ __launch_bounds__(448) void conv2f_mfma_k(
    const _Float16* __restrict__ xh, const _Float16* __restrict__ xl,
    const float* __restrict__ b1, const _Float16* __restrict__ w1p,
    const _Float16* __restrict__ w2p, const float* __restrict__ b2,
    _Float16* __restrict__ y2s) {
  __shared__ __align__(16) _Float16 S[31232];
  const int rp = blockIdx.x;
  const int img0 = blockIdx.y * 2;
  const int tid = threadIdx.x;

  const int w = tid >> 6;
  const int lane = tid & 63;
  const int l31 = lane & 31;
  const int g = lane >> 5;

  // ---- phase 1 (x2 img-phases): conv1 via MFMA; 6 m-tiles of 32 ----
  {
    const float b1c = b1[l31];
    const int gb = l31 >> 3, e0 = l31 & 7;
    int xoffs[16];
#pragma unroll
    for (int s = 0; s < 2; ++s)
#pragma unroll
      for (int e = 0; e < 8; ++e) {
        const int k = s * 16 + g * 8 + e;
        const int ky = k / 5, kx = k - (k / 5) * 5;
        xoffs[s * 8 + e] = (k < 25) ? (ky * 64 + kx) : -1;
      }
#pragma unroll 1
    for (int ph = 0; ph < 2; ++ph) {
      if (tid < 240) {
        const int plane = tid / 120;
        const int c8 = tid - plane * 120;
        const _Float16* src = (plane ? xl : xh) +
                              (size_t)(img0 + ph) * 4096 + rp * 512 + c8 * 8;
        *(float4*)&S[23040 + plane * 960 + c8 * 8] = *(const float4*)src;
      }
      __syncthreads();
      if (w < 6) {
        const int p = w * 32 + l31;
        const int pcl = (p < 180) ? p : 179;
        const int row = pcl / 30;
        const int col = pcl - row * 30;
        const int xb = (2 * row) * 64 + 2 * col;
        f32x16 acc_h = {}, acc_l = {};
#pragma unroll
        for (int s = 0; s < 2; ++s) {
          half8 ah, al;
#pragma unroll
          for (int e = 0; e < 8; ++e) {
            const int o = xoffs[s * 8 + e];
            _Float16 hv = (_Float16)0.f, lv = (_Float16)0.f;
            if (o >= 0) {
              hv = S[23040 + xb + o];
              lv = S[24000 + xb + o];
            }
            ah[e] = hv;
            al[e] = lv;
          }
          const _Float16* bp = w1p + ((s * 2 + g) * 32 + l31) * 8;
          half8 bh = *(const half8*)bp;
          half8 bl = *(const half8*)(bp + 1024);
          acc_h = __builtin_amdgcn_mfma_f32_32x32x16_f16(ah, bh, acc_h, 0, 0, 0);
          acc_l = __builtin_amdgcn_mfma_f32_32x32x16_f16(ah, bl, acc_l, 0, 0, 0);
          acc_l = __builtin_amdgcn_mfma_f32_32x32x16_f16(al, bh, acc_l, 0, 0, 0);
        }
#pragma unroll
        for (int r = 0; r < 16; ++r) {
          const int mrow = (r & 3) + 8 * (r >> 2) + 4 * g;
          const int pp = w * 32 + mrow;
          if (pp < 180) {
            const int cl = pp - (pp / 30) * 30;
            const int swz = (cl >> 1) & 3;
            const int addr = ph * 5760 + pp * 32 + ((gb ^ swz) << 3) + e0;
            const float val =
                fmaxf(acc_h[r] + acc_l[r] * 9.765625e-4f + b1c, 0.f);
            const _Float16 hh = (_Float16)val;
            S[addr] = hh;
            S[11520 + addr] = (_Float16)((val - (float)hh) * 1024.0f);
          }
        }
      }
      __syncthreads();
    }
  }

  const int m = w * 32 + l31;
  const int aimg = m / 112;
  const int apos = m - aimg * 112;
  const int ar = apos / 28;
  const int ax = apos - ar * 28;
  const int icg = g * 8;

  f32x16 acc00 = {}, acc01 = {}, acc10 = {}, acc11 = {};

  // ---- phase 2: conv2 MFMA; A from LDS, B staged per-tc in LDS ----
#pragma unroll 1
  for (int tc = 0; tc < 5; ++tc) {
    __syncthreads();
    const int tap0 = tc * 2;
    const int ntaps = (tc == 4) ? 1 : 2;
    for (int c = tid; c < ntaps * 256; c += 448) {
      *(float4*)&S[23040 + c * 8] = *(const float4*)&w2p[tap0 * 2048 + c * 8];
      *(float4*)&S[27136 + c * 8] =
          *(const float4*)&w2p[18432 + tap0 * 2048 + c * 8];
    }
    __syncthreads();
#pragma unroll 1
    for (int tl = 0; tl < ntaps; ++tl) {
      const int tap = tap0 + tl;
      const int ky = tap / 3;
      const int kx = tap - ky * 3;
      const int acol = ax + kx;
      const int swzA = ((acol >> 1) & 3) << 3;
      const int abase = aimg * 5760 + ((ar + ky) * 30 + acol) * 32;
#pragma unroll
      for (int s = 0; s < 2; ++s) {
        const int icoA = (s * 16 + icg) ^ swzA;
        const int bo0 = 23040 + (((tl * 2 + 0) * 2 + s) * 2 + g) * 256 + l31 * 8;
        const int bo1 = 23040 + (((tl * 2 + 1) * 2 + s) * 2 + g) * 256 + l31 * 8;
        half8 ah = *(const half8*)&S[abase + icoA];
        half8 al = *(const half8*)&S[11520 + abase + icoA];
        half8 bh0 = *(const half8*)&S[bo0];
        half8 bl0 = *(const half8*)&S[bo0 + 4096];
        half8 bh1 = *(const half8*)&S[bo1];
        half8 bl1 = *(const half8*)&S[bo1 + 4096];
        acc00 = __builtin_amdgcn_mfma_f32_32x32x16_f16(ah, bh0, acc00, 0, 0, 0);
        acc10 = __builtin_amdgcn_mfma_f32_32x32x16_f16(ah, bl0, acc10, 0, 0, 0);
        acc10 = __builtin_amdgcn_mfma_f32_32x32x16_f16(al, bh0, acc10, 0, 0, 0);
        acc01 = __builtin_amdgcn_mfma_f32_32x32x16_f16(ah, bh1, acc01, 0, 0, 0);
        acc11 = __builtin_amdgcn_mfma_f32_32x32x16_f16(ah, bl1, acc11, 0, 0, 0);
        acc11 = __builtin_amdgcn_mfma_f32_32x32x16_f16(al, bh1, acc11, 0, 0, 0);
      }
    }
  }

  // ---- pool + bias + relu + split store, per-img halves ([112][68] f32) ----
  float* sPool = (float*)S;
#pragma unroll 1
  for (int ph = 0; ph < 2; ++ph) {
    __syncthreads();
#pragma unroll
    for (int r = 0; r < 16; ++r) {
      const int mrow = (r & 3) + 8 * (r >> 2) + 4 * g;
      const int mo = w * 32 + mrow;
      const int srow = mo - ph * 112;
      if (srow >= 0 && srow < 112) {
        sPool[srow * 68 + l31] = acc00[r] + acc10[r] * 9.765625e-4f;
        sPool[srow * 68 + 32 + l31] = acc01[r] + acc11[r] * 9.765625e-4f;
      }
    }
    __syncthreads();
    if (tid < 224) {
      const int pr = tid / 112;
      const int r2 = tid - pr * 112;
      const int pc = r2 >> 3;
      const int blk = r2 & 7;
      const int m00 = pr * 56 + pc * 2;
      const float* s0 = &sPool[m00 * 68 + blk * 8];
      float rowv[4][8];
      *(float4*)&rowv[0][0] = *(const float4*)s0;
      *(float4*)&rowv[0][4] = *(const float4*)(s0 + 4);
      *(float4*)&rowv[1][0] = *(const float4*)(s0 + 68);
      *(float4*)&rowv[1][4] = *(const float4*)(s0 + 72);
      *(float4*)&rowv[2][0] = *(const float4*)(s0 + 28 * 68);
      *(float4*)&rowv[2][4] = *(const float4*)(s0 + 28 * 68 + 4);
      *(float4*)&rowv[3][0] = *(const float4*)(s0 + 29 * 68);
      *(float4*)&rowv[3][4] = *(const float4*)(s0 + 29 * 68 + 4);
      half8 hv, lv;
#pragma unroll
      for (int e = 0; e < 8; ++e) {
        const float mx = fmaxf(fmaxf(rowv[0][e], rowv[1][e]),
                               fmaxf(rowv[2][e], rowv[3][e]));
        const float val = fmaxf(mx + b2[blk * 8 + e], 0.f);
        const _Float16 hh = (_Float16)val;
        hv[e] = hh;
        lv[e] = (_Float16)((val - (float)hh) * 1024.0f);
      }
      const int posg = (rp * 2 + pr) * 14 + pc;
      const int icc = blk >> 2;
      const int slot = (blk & 3) ^ ((posg >> 1) & 3);
      _Float16* dh = y2s + (size_t)(img0 + ph) * 25088 + icc * 6272 +
                     posg * 32 + slot * 8;
      *(float4*)dh = *(float4*)&hv;
      *(float4*)(dh + 12544) = *(float4*)&lv;
    }
  }
}

// ---------------------------------------------------------------------------
// conv3 v4: B-fragments direct from w3p (global); only X staged in LDS.
// ---------------------------------------------------------------------------
__global__ __launch_bounds__(320) void conv3_mfma_k(
    const _Float16* __restrict__ y2s, const _Float16* __restrict__ w3p,
    const float* __restrict__ b3, _Float16* __restrict__ fh,
    _Float16* __restrict__ fl) {
  __shared__ __align__(16) _Float16 S[12544];
  const int img = blockIdx.x;
  const int tid = threadIdx.x;
  const int w = tid >> 6;
  const int lane = tid & 63;
  const int l31 = lane & 31;
  const int g = lane >> 5;
  const int m = w * 32 + l31;
  const int mc = (m < 144) ? m : 143;
  const int r = mc / 12, c = mc - (mc / 12) * 12;

  f32x16 acch[3] = {};
  f32x16 accl[3] = {};

  const _Float16* bb = w3p + g * 256 + l31 * 8;
#pragma unroll 1
  for (int icc = 0; icc < 2; ++icc) {
    __syncthreads();
    {
      const _Float16* src = y2s + (size_t)img * 25088 + icc * 6272;
      for (int c8 = tid; c8 < 784; c8 += 320) {
        *(float4*)&S[c8 * 8] = *(const float4*)&src[c8 * 8];
        *(float4*)&S[6272 + c8 * 8] = *(const float4*)&src[12544 + c8 * 8];
      }
    }
    __syncthreads();
#pragma unroll 1
    for (int tc = 0; tc < 5; ++tc) {
      const int ntaps = (tc == 4) ? 1 : 2;
#pragma unroll 1
      for (int tl = 0; tl < ntaps; ++tl) {
        const int tap = tc * 2 + tl;
        const int ky = tap / 3, kx = tap - (tap / 3) * 3;
        const int pix = (r + ky) * 14 + (c + kx);
        const int pswz = (pix >> 1) & 3;
        half8 ah[2], al[2];
#pragma unroll
        for (int s = 0; s < 2; ++s) {
          const int o = pix * 32 + ((s * 2 + g) ^ pswz) * 8;
          ah[s] = *(const half8*)&S[o];
          al[s] = *(const half8*)&S[6272 + o];
        }
        const _Float16* bt = bb + icc * 27648 + tc * 6144 + tl * 3072;
#pragma unroll
        for (int nt = 0; nt < 3; ++nt) {
#pragma unroll
          for (int s = 0; s < 2; ++s) {
            const _Float16* bp = bt + nt * 1024 + s * 512;
            half8 bh = *(const half8*)bp;
            half8 bl = *(const half8*)(bp + 55296);
            acch[nt] =
                __builtin_amdgcn_mfma_f32_32x32x16_f16(ah[s], bh, acch[nt], 0, 0, 0);
            accl[nt] =
                __builtin_amdgcn_mfma_f32_32x32x16_f16(ah[s], bl, accl[nt], 0, 0, 0);
            accl[nt] =
                __builtin_amdgcn_mfma_f32_32x32x16_f16(al[s], bh, accl[nt], 0, 0, 0);
          }
        }
      }
    }
  }
  float* sO = (float*)S;
#pragma unroll
  for (int nt = 0; nt < 3; ++nt) {
    __syncthreads();
#pragma unroll
    for (int rr = 0; rr < 16; ++rr) {
      const int row = (rr & 3) + 8 * (rr >> 2) + 4 * g;
      const int pos = w * 32 + row;
      if (pos < 144)
        sO[l31 * 145 + pos] = acch[nt][rr] + accl[nt][rr] * 9.765625e-4f;
    }
    __syncthreads();
    for (int idx8 = tid; idx8 < 576; idx8 += 320) {
      const int oc = idx8 / 18;
      const int pb = idx8 - oc * 18;
      const float bb2 = b3[nt * 32 + oc];
      half8 hv, lv;
#pragma unroll
      for (int e = 0; e < 8; ++e) {
        const float v = fmaxf(sO[oc * 145 + pb * 8 + e] + bb2, 0.f);
        const _Float16 hh = (_Float16)v;
        hv[e] = hh;
        lv[e] = (_Float16)((v - (float)hh) * 1024.0f);
      }
      const size_t ko = (size_t)img * 13824 + (nt * 32 + oc) * 144 + pb * 8;
      *(float4*)&fh[ko] = *(float4*)&hv;
      *(float4*)&fl[ko] = *(float4*)&lv;
    }
  }
}

// ---------------------------------------------------------------------------
// ff GEMM via MFMA split-f16 (unchanged).
// ---------------------------------------------------------------------------
__global__ __launch_bounds__(256) void ffgemm_k(
    const _Float16* __restrict__ fh, const _Float16* __restrict__ fl,
    const _Float16* __restrict__ winp, float* __restrict__ P, int frame0,
    int Cl) {
  __shared__ __align__(16) _Float16 S[24576];
  const int mb = blockIdx.x;
  const int kc = blockIdx.y;
  const int tid = threadIdx.x;
  const int w = tid >> 6;
  const int lane = tid & 63;
  const int l31 = lane & 31;
  const int g = lane >> 5;
  const int mt = w >> 1;
  const int nt0 = (w & 1) * 2;
  f32x16 acc_h[2] = {};
  f32x16 acc_l[2] = {};
  const int kbase = kc * 1728;
#pragma unroll 1
  for (int kt = 0; kt < 27; ++kt) {
    __syncthreads();
    for (int i = tid; i < 512; i += 256) {
      const int row = i >> 3, kb = i & 7;
      int rc = mb * 64 + row;
      if (rc >= Cl) rc = Cl - 1;
      const size_t so = (size_t)rc * 13824 + kbase + kt * 64 + kb * 8;
      const int d = row * 64 + ((kb ^ (row & 7)) * 8);
      *(float4*)&S[d] = *(const float4*)&fh[so];
      *(float4*)&S[4096 + d] = *(const float4*)&fl[so];
    }
    {
      const size_t bo = (size_t)(kc * 108 + kt * 4) * 2048;
      for (int i = tid; i < 1024; i += 256) {
        *(float4*)&S[8192 + i * 8] = *(const float4*)&winp[bo + i * 8];
        *(float4*)&S[16384 + i * 8] =
            *(const float4*)&winp[1769472 + bo + i * 8];
      }
    }
    __syncthreads();
#pragma unroll
    for (int ks = 0; ks < 4; ++ks) {
      const int kb = ks * 2 + g;
      const int ao = (mt * 32 + l31) * 64 + ((kb ^ (l31 & 7)) * 8);
      half8 ah = *(const half8*)&S[ao];
      half8 al = *(const half8*)&S[4096 + ao];
#pragma unroll
      for (int j = 0; j < 2; ++j) {
        const int nt = nt0 + j;
        const int b = 8192 + (((ks * 4 + nt) * 2 + g) * 32 + l31) * 8;
        half8 bh = *(const half8*)&S[b];
        half8 bl = *(const half8*)&S[8192 + b];
        acc_h[j] = __builtin_amdgcn_mfma_f32_32x32x16_f16(ah, bh, acc_h[j], 0, 0, 0);
        acc_l[j] = __builtin_amdgcn_mfma_f32_32x32x16_f16(ah, bl, acc_l[j], 0, 0, 0);
        acc_l[j] = __builtin_amdgcn_mfma_f32_32x32x16_f16(al, bh, acc_l[j], 0, 0, 0);
      }
    }
  }
  float* Pp = P + ((size_t)kc * 2048 + (size_t)frame0) * 128;
#pragma unroll
  for (int j = 0; j < 2; ++j) {
    const int h = (nt0 + j) * 32 + l31;
#pragma unroll
    for (int r = 0; r < 16; ++r) {
      const int row = (r & 3) + 8 * (r >> 2) + 4 * g;
      const int fr = mb * 64 + mt * 32 + row;
      if (fr < Cl)
        Pp[(size_t)fr * 128 + h] = acc_h[j][r] + acc_l[j][r] * 9.765625e-4f;
    }
  }
}

__global__ __launch_bounds__(256) void ffreduce_k(const float* __restrict__ P,
                                                  float* __restrict__ ffo) {
  const int i = blockIdx.x * 256 + threadIdx.x;
  float s = 0.f;
#pragma unroll
  for (int kcc = 0; kcc < 8; ++kcc) s += P[(size_t)kcc * 262144 + i];
  ffo[i] = s;
}

// ---------------------------------------------------------------------------
// Recurrent LIF scan (unchanged)
// ---------------------------------------------------------------------------
__global__ __launch_bounds__(64) void scan_k(
    const float* __restrict__ ff, const float* __restrict__ w_rec,
    const float* __restrict__ w_fc, const float* __restrict__ b_fc,
    float* __restrict__ out) {
#pragma clang fp contract(off)
  __shared__ float sWr[16384];
  const int b = blockIdx.x;
  const int t = threadIdx.x;
  for (int idx = t; idx < 16384; idx += 64) {
    int hh = idx >> 7, j = idx & 127;
    sWr[j * 128 + hh] = w_rec[idx];
  }
  float wf0[10], wf1[10], bf[10];
#pragma unroll
  for (int c = 0; c < 10; ++c) {
    wf0[c] = w_fc[c * 128 + t];
    wf1[c] = w_fc[c * 128 + 64 + t];
    bf[c] = b_fc[c];
  }
  __syncthreads();
  float v0 = 0.f, v1 = 0.f, i0 = 0.f, i1 = 0.f;
  float vr[10], ir[10], vmax[10];
#pragma unroll
  for (int c = 0; c < 10; ++c) {
    vr[c] = 0.f;
    ir[c] = 0.f;
    vmax[c] = -1e30f;
  }
  unsigned long long pm0 = 0ull, pm1 = 0ull;
  const float* ffb = ff + (size_t)b * 8192;
#pragma unroll 1
  for (int ts = 0; ts < 64; ++ts) {
    const float vd0 = v0 + 0.1f * (i0 - v0);
    const float vd1 = v1 + 0.1f * (i1 - v1);
    const float id0 = i0 - 0.2f * i0;
    const float id1 = i1 - 0.2f * i1;
    const bool z0 = (vd0 - 0.4f) > 0.f;
    const bool z1 = (vd1 - 0.4f) > 0.f;
    v0 = z0 ? 0.f : vd0;
    v1 = z1 ? 0.f : vd1;
    float rec0 = 0.f, rec1 = 0.f;
    unsigned long long mm = pm0;
    while (mm) {
      int j = __ffsll(mm) - 1;
      mm &= mm - 1;
      rec0 += sWr[j * 128 + t];
      rec1 += sWr[j * 128 + t + 64];
    }
    mm = pm1;
    while (mm) {
      int j = __ffsll(mm) - 1;
      mm &= mm - 1;
      rec0 += sWr[(j + 64) * 128 + t];
      rec1 += sWr[(j + 64) * 128 + t + 64];
    }
    i0 = (id0 + ffb[ts * 128 + t]) + rec0;
    i1 = (id1 + ffb[ts * 128 + 64 + t]) + rec1;
    pm0 = __ballot(z0);
    pm1 = __ballot(z1);
#pragma unroll
    for (int c = 0; c < 10; ++c) {
      float val = (z0 ? wf0[c] : 0.f) + (z1 ? wf1[c] : 0.f);
      val += __shfl_xor(val, 1);
      val += __shfl_xor(val, 2);
      val += __shfl_xor(val, 4);
      val += __shfl_xor(val, 8);
      val += __shfl_xor(val, 16);
      val += __shfl_xor(val, 32);
      const float ro = val + bf[c];
      vr[c] = vr[c] + 0.1f * (ir[c] - vr[c]);
      vmax[c] = fmaxf(vmax[c], vr[c]);
      ir[c] = (ir[c] - 0.2f * ir[c]) + ro;
    }
  }
  if (t == 0) {
    float M = vmax[0];
#pragma unroll
    for (int c = 1; c < 10; ++c) M = fmaxf(M, vmax[c]);
    float s = 0.f;
#pragma unroll
    for (int c = 0; c < 10; ++c) s += expf(vmax[c] - M);
    const float ls = logf(s);
#pragma unroll
    for (int c = 0; c < 10; ++c) out[b * 10 + c] = vmax[c] - M - ls;
  }
}

// ---------------------------------------------------------------------------
extern "C" void kernel_launch(void* const* d_in, const int* in_sizes, int n_in,
                              void* d_out, int out_size, void* d_ws,
                              size_t ws_size, hipStream_t stream) {
  (void)in_sizes;
  (void)n_in;
  (void)out_size;
  const float* x = (const float*)d_in[0];
  const float* w1 = (const float*)d_in[1];
  const float* b1 = (const float*)d_in[2];
  const float* w2 = (const float*)d_in[3];
  const float* b2 = (const float*)d_in[4];
  const float* w3 = (const float*)d_in[5];
  const float* b3 = (const float*)d_in[6];
  const float* w_in = (const float*)d_in[7];
  const float* w_rec = (const float*)d_in[8];
  const float* w_fc = (const float*)d_in[9];
  const float* b_fc = (const float*)d_in[10];
  float* out = (float*)d_out;
  char* ws = (char*)d_ws;

  // ws: ff 1MB | P 8MB | w2p | w3p | winp | w1p | xh | xl | per-chunk bufs
  const size_t OFF_W2P = 1048576ull + 8388608ull;     // 9,437,184
  const size_t OFF_W3P = OFF_W2P + 147456ull;         // 9,584,640
  const size_t OFF_WIN = OFF_W3P + 221184ull;         // 9,805,824
  const size_t OFF_W1P = OFF_WIN + 7077888ull;        // 16,883,712
  const size_t OFF_XH = OFF_W1P + 8192ull;            // 16,891,904
  const size_t OFF_XL = OFF_XH + 16777216ull;         // 33,669,120
  const size_t HDR = OFF_XL + 16777216ull;            // 50,446,336
  const size_t PERF = 50176ull + 55296ull;            // 105,472
  int C = 32;
  for (int c = 2048; c >= 32; c >>= 1) {
    if (HDR + (size_t)c * PERF <= ws_size) { C = c; break; }
  }
  float* ffbuf = (float*)ws;
  float* P = (float*)(ws + 1048576ull);
  _Float16* w2p = (_Float16*)(ws + OFF_W2P);
  _Float16* w3p = (_Float16*)(ws + OFF_W3P);
  _Float16* winp = (_Float16*)(ws + OFF_WIN);
  _Float16* w1p = (_Float16*)(ws + OFF_W1P);
  _Float16* xh = (_Float16*)(ws + OFF_XH);
  _Float16* xl = (_Float16*)(ws + OFF_XL);
  _Float16* y2s = (_Float16*)(ws + HDR);
  _Float16* fh = (_Float16*)(ws + HDR + (size_t)C * 50176ull);
  _Float16* fl = fh + (size_t)C * 13824;

  xprep_k<<<8192, 256, 0, stream>>>(x, xh, xl);
  w1prep_k<<<4, 256, 0, stream>>>(w1, w1p);
  w2prep_k<<<72, 256, 0, stream>>>(w2, w2p);
  w3prep_k<<<216, 256, 0, stream>>>(w3, w3p);
  winprep_k<<<6912, 256, 0, stream>>>(w_in, winp);

  const int nChunks = 2048 / C;
  const int mbN = (C + 63) / 64;
  for (int ch = 0; ch < nChunks; ++ch) {
    const int f0 = ch * C;
    conv2f_mfma_k<<<dim3(7, C / 2), 448, 0, stream>>>(
        xh + (size_t)f0 * 4096, xl + (size_t)f0 * 4096, b1, w1p, w2p, b2, y2s);
    conv3_mfma_k<<<C, 320, 0, stream>>>(y2s, w3p, b3, fh, fl);
    ffgemm_k<<<dim3(mbN, 8), 256, 0, stream>>>(fh, fl, winp, P, f0, C);
  }
  ffreduce_k<<<1024, 256, 0, stream>>>(P, ffbuf);
  scan_k<<<32, 64, 0, stream>>>(ffbuf, w_rec, w_fc, b_fc, out);
}

// Round 21
// 578.375 us; speedup vs baseline: 1.0248x; 1.0248x over previous
//
#include <hip/hip_runtime.h>
#include <math.h>

typedef _Float16 half8 __attribute__((ext_vector_type(8)));
typedef _Float16 half4 __attribute__((ext_vector_type(4)));
typedef float f32x16 __attribute__((ext_vector_type(16)));

// ---------------------------------------------------------------------------
// xprep: split x (f32) into global f16 hi/lo planes (one-shot).
// ---------------------------------------------------------------------------
__global__ __launch_bounds__(256) void xprep_k(const float* __restrict__ x,
                                               _Float16* __restrict__ xh,
                                               _Float16* __restrict__ xl) {
  const int i = blockIdx.x * 256 + threadIdx.x;  // x4 floats
  if (i >= 2097152) return;
  const float4 v = *(const float4*)(x + (size_t)i * 4);
  half4 h, l;
  const float vv[4] = {v.x, v.y, v.z, v.w};
#pragma unroll
  for (int e = 0; e < 4; ++e) {
    const _Float16 hh = (_Float16)vv[e];
    h[e] = hh;
    l[e] = (_Float16)((vv[e] - (float)hh) * 1024.0f);
  }
  *(half4*)(xh + (size_t)i * 4) = h;
  *(half4*)(xl + (size_t)i * 4) = l;
}

// ---------------------------------------------------------------------------
// w1prep: conv1-MFMA B-fragment order, split hi/lo, K padded 25->32.
// ---------------------------------------------------------------------------
__global__ __launch_bounds__(256) void w1prep_k(const float* __restrict__ w1,
                                                _Float16* __restrict__ w1p) {
  const int i = blockIdx.x * 256 + threadIdx.x;
  if (i >= 1024) return;
  const int blk = i >> 8;
  const int s = blk >> 1, g = blk & 1;
  const int ch = (i >> 3) & 31, e = i & 7;
  const int k = s * 16 + g * 8 + e;
  float v = 0.f;
  if (k < 25) v = w1[ch * 25 + k];
  const _Float16 h = (_Float16)v;
  w1p[i] = h;
  w1p[1024 + i] = (_Float16)((v - (float)h) * 1024.0f);
}

// ---------------------------------------------------------------------------
// w2prep: pack w2 into MFMA-fragment order, split hi/lo f16.
// ---------------------------------------------------------------------------
__global__ __launch_bounds__(256) void w2prep_k(const float* __restrict__ w2,
                                                _Float16* __restrict__ w2p) {
  const int i = blockIdx.x * 256 + threadIdx.x;
  if (i >= 18432) return;
  const int tap = i >> 11;
  const int r = i & 2047;
  const int blk = r >> 8;
  const int nt = blk >> 2, s = (blk >> 1) & 1, g = blk & 1;
  const int n = (r >> 3) & 31, e = r & 7;
  const int och = nt * 32 + n;
  const int ic = s * 16 + g * 8 + e;
  const float v = w2[och * 288 + ic * 9 + tap];
  const _Float16 h = (_Float16)v;
  const _Float16 l = (_Float16)((v - (float)h) * 1024.0f);
  w2p[i] = h;
  w2p[18432 + i] = l;
}

// ---------------------------------------------------------------------------
// w3prep: pack w3 into conv3's fragment-order image.
// ---------------------------------------------------------------------------
__global__ __launch_bounds__(256) void w3prep_k(const float* __restrict__ w3,
                                                _Float16* __restrict__ w3p) {
  const int i = blockIdx.x * 256 + threadIdx.x;
  if (i >= 55296) return;
  const int icc = i / 27648;
  const int r1 = i - icc * 27648;
  const int tc = r1 / 6144;
  const int rem = r1 - tc * 6144;
  const int tl = rem / 3072;
  const int rem2 = rem - tl * 3072;
  const int nt = rem2 >> 10;
  const int s = (rem2 >> 9) & 1;
  const int g = (rem2 >> 8) & 1;
  const int n = (rem2 >> 3) & 31;
  const int e = rem2 & 7;
  const int tap = tc * 2 + tl;
  const int och = nt * 32 + n;
  const int ic = icc * 32 + s * 16 + g * 8 + e;
  const float v = w3[(size_t)och * 576 + ic * 9 + tap];
  const _Float16 h = (_Float16)v;
  const _Float16 l = (_Float16)((v - (float)h) * 1024.0f);
  w3p[i] = h;
  w3p[55296 + i] = l;
}

// ---------------------------------------------------------------------------
// winprep: pack w_in into ff-GEMM B-fragment order, split f16.
// ---------------------------------------------------------------------------
__global__ __launch_bounds__(256) void winprep_k(const float* __restrict__ w_in,
                                                 _Float16* __restrict__ winp) {
  const int i = blockIdx.x * 256 + threadIdx.x;
  if (i >= 1769472) return;
  const int ks = i >> 11;
  const int rem = i & 2047;
  const int nt = rem >> 9;
  const int g = (rem >> 8) & 1;
  const int n = (rem >> 3) & 31;
  const int e = rem & 7;
  const int h = nt * 32 + n;
  const int k = ks * 16 + g * 8 + e;
  const float v = w_in[(size_t)h * 13824 + k];
  const _Float16 hh = (_Float16)v;
  const _Float16 ll = (_Float16)((v - (float)hh) * 1024.0f);
  winp[i] = hh;
  winp[1769472 + i] = ll;
}

// ---------------------------------------------------------------------------
// conv2f v7: FUSED conv1(MFMA) + conv2(MFMA) + maxpool (unchanged from R20).
// ---------------------------------------------------------------------------
__global__ __launch_bounds__(448) void conv2f_mfma_k(
    const _Float16* __restrict__ xh, const _Float16* __restrict__ xl,
    const float* __restrict__ b1, const _Float16* __restrict__ w1p,
    const _Float16* __restrict__ w2p, const float* __restrict__ b2,
    _Float16* __restrict__ y2s) {
  __shared__ __align__(16) _Float16 S[31232];
  const int rp = blockIdx.x;
  const int img0 = blockIdx.y * 2;
  const int tid = threadIdx.x;

  const int w = tid >> 6;
  const int lane = tid & 63;
  const int l31 = lane & 31;
  const int g = lane >> 5;

  // ---- phase 1 (x2 img-phases): conv1 via MFMA; 6 m-tiles of 32 ----
  {
    const float b1c = b1[l31];
    const int gb = l31 >> 3, e0 = l31 & 7;
    int xoffs[16];
#pragma unroll
    for (int s = 0; s < 2; ++s)
#pragma unroll
      for (int e = 0; e < 8; ++e) {
        const int k = s * 16 + g * 8 + e;
        const int ky = k / 5, kx = k - (k / 5) * 5;
        xoffs[s * 8 + e] = (k < 25) ? (ky * 64 + kx) : -1;
      }
#pragma unroll 1
    for (int ph = 0; ph < 2; ++ph) {
      if (tid < 240) {
        const int plane = tid / 120;
        const int c8 = tid - plane * 120;
        const _Float16* src = (plane ? xl : xh) +
                              (size_t)(img0 + ph) * 4096 + rp * 512 + c8 * 8;
        *(float4*)&S[23040 + plane * 960 + c8 * 8] = *(const float4*)src;
      }
      __syncthreads();
      if (w < 6) {
        const int p = w * 32 + l31;
        const int pcl = (p < 180) ? p : 179;
        const int row = pcl / 30;
        const int col = pcl - row * 30;
        const int xb = (2 * row) * 64 + 2 * col;
        f32x16 acc_h = {}, acc_l = {};
#pragma unroll
        for (int s = 0; s < 2; ++s) {
          half8 ah, al;
#pragma unroll
          for (int e = 0; e < 8; ++e) {
            const int o = xoffs[s * 8 + e];
            _Float16 hv = (_Float16)0.f, lv = (_Float16)0.f;
            if (o >= 0) {
              hv = S[23040 + xb + o];
              lv = S[24000 + xb + o];
            }
            ah[e] = hv;
            al[e] = lv;
          }
          const _Float16* bp = w1p + ((s * 2 + g) * 32 + l31) * 8;
          half8 bh = *(const half8*)bp;
          half8 bl = *(const half8*)(bp + 1024);
          acc_h = __builtin_amdgcn_mfma_f32_32x32x16_f16(ah, bh, acc_h, 0, 0, 0);
          acc_l = __builtin_amdgcn_mfma_f32_32x32x16_f16(ah, bl, acc_l, 0, 0, 0);
          acc_l = __builtin_amdgcn_mfma_f32_32x32x16_f16(al, bh, acc_l, 0, 0, 0);
        }
#pragma unroll
        for (int r = 0; r < 16; ++r) {
          const int mrow = (r & 3) + 8 * (r >> 2) + 4 * g;
          const int pp = w * 32 + mrow;
          if (pp < 180) {
            const int cl = pp - (pp / 30) * 30;
            const int swz = (cl >> 1) & 3;
            const int addr = ph * 5760 + pp * 32 + ((gb ^ swz) << 3) + e0;
            const float val =
                fmaxf(acc_h[r] + acc_l[r] * 9.765625e-4f + b1c, 0.f);
            const _Float16 hh = (_Float16)val;
            S[addr] = hh;
            S[11520 + addr] = (_Float16)((val - (float)hh) * 1024.0f);
          }
        }
      }
      __syncthreads();
    }
  }

  const int m = w * 32 + l31;
  const int aimg = m / 112;
  const int apos = m - aimg * 112;
  const int ar = apos / 28;
  const int ax = apos - ar * 28;
  const int icg = g * 8;

  f32x16 acc00 = {}, acc01 = {}, acc10 = {}, acc11 = {};

  // ---- phase 2: conv2 MFMA; A from LDS, B staged per-tc in LDS ----
#pragma unroll 1
  for (int tc = 0; tc < 5; ++tc) {
    __syncthreads();
    const int tap0 = tc * 2;
    const int ntaps = (tc == 4) ? 1 : 2;
    for (int c = tid; c < ntaps * 256; c += 448) {
      *(float4*)&S[23040 + c * 8] = *(const float4*)&w2p[tap0 * 2048 + c * 8];
      *(float4*)&S[27136 + c * 8] =
          *(const float4*)&w2p[18432 + tap0 * 2048 + c * 8];
    }
    __syncthreads();
#pragma unroll 1
    for (int tl = 0; tl < ntaps; ++tl) {
      const int tap = tap0 + tl;
      const int ky = tap / 3;
      const int kx = tap - ky * 3;
      const int acol = ax + kx;
      const int swzA = ((acol >> 1) & 3) << 3;
      const int abase = aimg * 5760 + ((ar + ky) * 30 + acol) * 32;
#pragma unroll
      for (int s = 0; s < 2; ++s) {
        const int icoA = (s * 16 + icg) ^ swzA;
        const int bo0 = 23040 + (((tl * 2 + 0) * 2 + s) * 2 + g) * 256 + l31 * 8;
        const int bo1 = 23040 + (((tl * 2 + 1) * 2 + s) * 2 + g) * 256 + l31 * 8;
        half8 ah = *(const half8*)&S[abase + icoA];
        half8 al = *(const half8*)&S[11520 + abase + icoA];
        half8 bh0 = *(const half8*)&S[bo0];
        half8 bl0 = *(const half8*)&S[bo0 + 4096];
        half8 bh1 = *(const half8*)&S[bo1];
        half8 bl1 = *(const half8*)&S[bo1 + 4096];
        acc00 = __builtin_amdgcn_mfma_f32_32x32x16_f16(ah, bh0, acc00, 0, 0, 0);
        acc10 = __builtin_amdgcn_mfma_f32_32x32x16_f16(ah, bl0, acc10, 0, 0, 0);
        acc10 = __builtin_amdgcn_mfma_f32_32x32x16_f16(al, bh0, acc10, 0, 0, 0);
        acc01 = __builtin_amdgcn_mfma_f32_32x32x16_f16(ah, bh1, acc01, 0, 0, 0);
        acc11 = __builtin_amdgcn_mfma_f32_32x32x16_f16(ah, bl1, acc11, 0, 0, 0);
        acc11 = __builtin_amdgcn_mfma_f32_32x32x16_f16(al, bh1, acc11, 0, 0, 0);
      }
    }
  }

  // ---- pool + bias + relu + split store, per-img halves ([112][68] f32) ----
  float* sPool = (float*)S;
#pragma unroll 1
  for (int ph = 0; ph < 2; ++ph) {
    __syncthreads();
#pragma unroll
    for (int r = 0; r < 16; ++r) {
      const int mrow = (r & 3) + 8 * (r >> 2) + 4 * g;
      const int mo = w * 32 + mrow;
      const int srow = mo - ph * 112;
      if (srow >= 0 && srow < 112) {
        sPool[srow * 68 + l31] = acc00[r] + acc10[r] * 9.765625e-4f;
        sPool[srow * 68 + 32 + l31] = acc01[r] + acc11[r] * 9.765625e-4f;
      }
    }
    __syncthreads();
    if (tid < 224) {
      const int pr = tid / 112;
      const int r2 = tid - pr * 112;
      const int pc = r2 >> 3;
      const int blk = r2 & 7;
      const int m00 = pr * 56 + pc * 2;
      const float* s0 = &sPool[m00 * 68 + blk * 8];
      float rowv[4][8];
      *(float4*)&rowv[0][0] = *(const float4*)s0;
      *(float4*)&rowv[0][4] = *(const float4*)(s0 + 4);
      *(float4*)&rowv[1][0] = *(const float4*)(s0 + 68);
      *(float4*)&rowv[1][4] = *(const float4*)(s0 + 72);
      *(float4*)&rowv[2][0] = *(const float4*)(s0 + 28 * 68);
      *(float4*)&rowv[2][4] = *(const float4*)(s0 + 28 * 68 + 4);
      *(float4*)&rowv[3][0] = *(const float4*)(s0 + 29 * 68);
      *(float4*)&rowv[3][4] = *(const float4*)(s0 + 29 * 68 + 4);
      half8 hv, lv;
#pragma unroll
      for (int e = 0; e < 8; ++e) {
        const float mx = fmaxf(fmaxf(rowv[0][e], rowv[1][e]),
                               fmaxf(rowv[2][e], rowv[3][e]));
        const float val = fmaxf(mx + b2[blk * 8 + e], 0.f);
        const _Float16 hh = (_Float16)val;
        hv[e] = hh;
        lv[e] = (_Float16)((val - (float)hh) * 1024.0f);
      }
      const int posg = (rp * 2 + pr) * 14 + pc;
      const int icc = blk >> 2;
      const int slot = (blk & 3) ^ ((posg >> 1) & 3);
      _Float16* dh = y2s + (size_t)(img0 + ph) * 25088 + icc * 6272 +
                     posg * 32 + slot * 8;
      *(float4*)dh = *(float4*)&hv;
      *(float4*)(dh + 12544) = *(float4*)&lv;
    }
  }
}

// ---------------------------------------------------------------------------
// conv3 v4: B-fragments direct from w3p (global); only X staged in LDS.
// ---------------------------------------------------------------------------
__global__ __launch_bounds__(320) void conv3_mfma_k(
    const _Float16* __restrict__ y2s, const _Float16* __restrict__ w3p,
    const float* __restrict__ b3, _Float16* __restrict__ fh,
    _Float16* __restrict__ fl) {
  __shared__ __align__(16) _Float16 S[12544];
  const int img = blockIdx.x;
  const int tid = threadIdx.x;
  const int w = tid >> 6;
  const int lane = tid & 63;
  const int l31 = lane & 31;
  const int g = lane >> 5;
  const int m = w * 32 + l31;
  const int mc = (m < 144) ? m : 143;
  const int r = mc / 12, c = mc - (mc / 12) * 12;

  f32x16 acch[3] = {};
  f32x16 accl[3] = {};

  const _Float16* bb = w3p + g * 256 + l31 * 8;
#pragma unroll 1
  for (int icc = 0; icc < 2; ++icc) {
    __syncthreads();
    {
      const _Float16* src = y2s + (size_t)img * 25088 + icc * 6272;
      for (int c8 = tid; c8 < 784; c8 += 320) {
        *(float4*)&S[c8 * 8] = *(const float4*)&src[c8 * 8];
        *(float4*)&S[6272 + c8 * 8] = *(const float4*)&src[12544 + c8 * 8];
      }
    }
    __syncthreads();
#pragma unroll 1
    for (int tc = 0; tc < 5; ++tc) {
      const int ntaps = (tc == 4) ? 1 : 2;
#pragma unroll 1
      for (int tl = 0; tl < ntaps; ++tl) {
        const int tap = tc * 2 + tl;
        const int ky = tap / 3, kx = tap - (tap / 3) * 3;
        const int pix = (r + ky) * 14 + (c + kx);
        const int pswz = (pix >> 1) & 3;
        half8 ah[2], al[2];
#pragma unroll
        for (int s = 0; s < 2; ++s) {
          const int o = pix * 32 + ((s * 2 + g) ^ pswz) * 8;
          ah[s] = *(const half8*)&S[o];
          al[s] = *(const half8*)&S[6272 + o];
        }
        const _Float16* bt = bb + icc * 27648 + tc * 6144 + tl * 3072;
#pragma unroll
        for (int nt = 0; nt < 3; ++nt) {
#pragma unroll
          for (int s = 0; s < 2; ++s) {
            const _Float16* bp = bt + nt * 1024 + s * 512;
            half8 bh = *(const half8*)bp;
            half8 bl = *(const half8*)(bp + 55296);
            acch[nt] =
                __builtin_amdgcn_mfma_f32_32x32x16_f16(ah[s], bh, acch[nt], 0, 0, 0);
            accl[nt] =
                __builtin_amdgcn_mfma_f32_32x32x16_f16(ah[s], bl, accl[nt], 0, 0, 0);
            accl[nt] =
                __builtin_amdgcn_mfma_f32_32x32x16_f16(al[s], bh, accl[nt], 0, 0, 0);
          }
        }
      }
    }
  }
  float* sO = (float*)S;
#pragma unroll
  for (int nt = 0; nt < 3; ++nt) {
    __syncthreads();
#pragma unroll
    for (int rr = 0; rr < 16; ++rr) {
      const int row = (rr & 3) + 8 * (rr >> 2) + 4 * g;
      const int pos = w * 32 + row;
      if (pos < 144)
        sO[l31 * 145 + pos] = acch[nt][rr] + accl[nt][rr] * 9.765625e-4f;
    }
    __syncthreads();
    for (int idx8 = tid; idx8 < 576; idx8 += 320) {
      const int oc = idx8 / 18;
      const int pb = idx8 - oc * 18;
      const float bb2 = b3[nt * 32 + oc];
      half8 hv, lv;
#pragma unroll
      for (int e = 0; e < 8; ++e) {
        const float v = fmaxf(sO[oc * 145 + pb * 8 + e] + bb2, 0.f);
        const _Float16 hh = (_Float16)v;
        hv[e] = hh;
        lv[e] = (_Float16)((v - (float)hh) * 1024.0f);
      }
      const size_t ko = (size_t)img * 13824 + (nt * 32 + oc) * 144 + pb * 8;
      *(float4*)&fh[ko] = *(float4*)&hv;
      *(float4*)&fl[ko] = *(float4*)&lv;
    }
  }
}

// ---------------------------------------------------------------------------
// ff GEMM via MFMA split-f16, BM=32: grid (C/32, 8), 2 blocks/CU, 8 waves/CU.
// LDS 40,960 B: Ah[0,2048) Al[2048,4096) Bh[4096,12288) Bl[12288,20480).
// Wave w = n-tile (4 n-tiles of 32); single m-tile of 32 rows.
// ---------------------------------------------------------------------------
__global__ __launch_bounds__(256) void ffgemm_k(
    const _Float16* __restrict__ fh, const _Float16* __restrict__ fl,
    const _Float16* __restrict__ winp, float* __restrict__ P, int frame0,
    int Cl) {
  __shared__ __align__(16) _Float16 S[20480];
  const int mb = blockIdx.x;
  const int kc = blockIdx.y;
  const int tid = threadIdx.x;
  const int w = tid >> 6;
  const int lane = tid & 63;
  const int l31 = lane & 31;
  const int g = lane >> 5;
  f32x16 acc_h = {};
  f32x16 acc_l = {};
  const int kbase = kc * 1728;
#pragma unroll 1
  for (int kt = 0; kt < 27; ++kt) {
    __syncthreads();
    {  // stage A: 32 rows x 64 k, slot-XOR kb^(row&7), both planes
      const int row = tid >> 3, kb = tid & 7;
      int rc = mb * 32 + row;
      if (rc >= Cl) rc = Cl - 1;
      const size_t so = (size_t)rc * 13824 + kbase + kt * 64 + kb * 8;
      const int d = row * 64 + ((kb ^ (row & 7)) * 8);
      *(float4*)&S[d] = *(const float4*)&fh[so];
      *(float4*)&S[2048 + d] = *(const float4*)&fl[so];
    }
    {  // stage B: linear copy of packed slice (4 ks x 2048)
      const size_t bo = (size_t)(kc * 108 + kt * 4) * 2048;
      for (int i = tid; i < 1024; i += 256) {
        *(float4*)&S[4096 + i * 8] = *(const float4*)&winp[bo + i * 8];
        *(float4*)&S[12288 + i * 8] =
            *(const float4*)&winp[1769472 + bo + i * 8];
      }
    }
    __syncthreads();
#pragma unroll
    for (int ks = 0; ks < 4; ++ks) {
      const int kb = ks * 2 + g;
      const int ao = l31 * 64 + ((kb ^ (l31 & 7)) * 8);
      half8 ah = *(const half8*)&S[ao];
      half8 al = *(const half8*)&S[2048 + ao];
      const int b = 4096 + (((ks * 4 + w) * 2 + g) * 32 + l31) * 8;
      half8 bh = *(const half8*)&S[b];
      half8 bl = *(const half8*)&S[b + 8192];
      acc_h = __builtin_amdgcn_mfma_f32_32x32x16_f16(ah, bh, acc_h, 0, 0, 0);
      acc_l = __builtin_amdgcn_mfma_f32_32x32x16_f16(ah, bl, acc_l, 0, 0, 0);
      acc_l = __builtin_amdgcn_mfma_f32_32x32x16_f16(al, bh, acc_l, 0, 0, 0);
    }
  }
  float* Pp = P + ((size_t)kc * 2048 + (size_t)frame0) * 128;
  const int h = w * 32 + l31;
#pragma unroll
  for (int r = 0; r < 16; ++r) {
    const int row = (r & 3) + 8 * (r >> 2) + 4 * g;
    const int fr = mb * 32 + row;
    if (fr < Cl) Pp[(size_t)fr * 128 + h] = acc_h[r] + acc_l[r] * 9.765625e-4f;
  }
}

__global__ __launch_bounds__(256) void ffreduce_k(const float* __restrict__ P,
                                                  float* __restrict__ ffo) {
  const int i = blockIdx.x * 256 + threadIdx.x;
  float s = 0.f;
#pragma unroll
  for (int kcc = 0; kcc < 8; ++kcc) s += P[(size_t)kcc * 262144 + i];
  ffo[i] = s;
}

// ---------------------------------------------------------------------------
// Recurrent LIF scan (unchanged)
// ---------------------------------------------------------------------------
__global__ __launch_bounds__(64) void scan_k(
    const float* __restrict__ ff, const float* __restrict__ w_rec,
    const float* __restrict__ w_fc, const float* __restrict__ b_fc,
    float* __restrict__ out) {
#pragma clang fp contract(off)
  __shared__ float sWr[16384];
  const int b = blockIdx.x;
  const int t = threadIdx.x;
  for (int idx = t; idx < 16384; idx += 64) {
    int hh = idx >> 7, j = idx & 127;
    sWr[j * 128 + hh] = w_rec[idx];
  }
  float wf0[10], wf1[10], bf[10];
#pragma unroll
  for (int c = 0; c < 10; ++c) {
    wf0[c] = w_fc[c * 128 + t];
    wf1[c] = w_fc[c * 128 + 64 + t];
    bf[c] = b_fc[c];
  }
  __syncthreads();
  float v0 = 0.f, v1 = 0.f, i0 = 0.f, i1 = 0.f;
  float vr[10], ir[10], vmax[10];
#pragma unroll
  for (int c = 0; c < 10; ++c) {
    vr[c] = 0.f;
    ir[c] = 0.f;
    vmax[c] = -1e30f;
  }
  unsigned long long pm0 = 0ull, pm1 = 0ull;
  const float* ffb = ff + (size_t)b * 8192;
#pragma unroll 1
  for (int ts = 0; ts < 64; ++ts) {
    const float vd0 = v0 + 0.1f * (i0 - v0);
    const float vd1 = v1 + 0.1f * (i1 - v1);
    const float id0 = i0 - 0.2f * i0;
    const float id1 = i1 - 0.2f * i1;
    const bool z0 = (vd0 - 0.4f) > 0.f;
    const bool z1 = (vd1 - 0.4f) > 0.f;
    v0 = z0 ? 0.f : vd0;
    v1 = z1 ? 0.f : vd1;
    float rec0 = 0.f, rec1 = 0.f;
    unsigned long long mm = pm0;
    while (mm) {
      int j = __ffsll(mm) - 1;
      mm &= mm - 1;
      rec0 += sWr[j * 128 + t];
      rec1 += sWr[j * 128 + t + 64];
    }
    mm = pm1;
    while (mm) {
      int j = __ffsll(mm) - 1;
      mm &= mm - 1;
      rec0 += sWr[(j + 64) * 128 + t];
      rec1 += sWr[(j + 64) * 128 + t + 64];
    }
    i0 = (id0 + ffb[ts * 128 + t]) + rec0;
    i1 = (id1 + ffb[ts * 128 + 64 + t]) + rec1;
    pm0 = __ballot(z0);
    pm1 = __ballot(z1);
#pragma unroll
    for (int c = 0; c < 10; ++c) {
      float val = (z0 ? wf0[c] : 0.f) + (z1 ? wf1[c] : 0.f);
      val += __shfl_xor(val, 1);
      val += __shfl_xor(val, 2);
      val += __shfl_xor(val, 4);
      val += __shfl_xor(val, 8);
      val += __shfl_xor(val, 16);
      val += __shfl_xor(val, 32);
      const float ro = val + bf[c];
      vr[c] = vr[c] + 0.1f * (ir[c] - vr[c]);
      vmax[c] = fmaxf(vmax[c], vr[c]);
      ir[c] = (ir[c] - 0.2f * ir[c]) + ro;
    }
  }
  if (t == 0) {
    float M = vmax[0];
#pragma unroll
    for (int c = 1; c < 10; ++c) M = fmaxf(M, vmax[c]);
    float s = 0.f;
#pragma unroll
    for (int c = 0; c < 10; ++c) s += expf(vmax[c] - M);
    const float ls = logf(s);
#pragma unroll
    for (int c = 0; c < 10; ++c) out[b * 10 + c] = vmax[c] - M - ls;
  }
}

// ---------------------------------------------------------------------------
extern "C" void kernel_launch(void* const* d_in, const int* in_sizes, int n_in,
                              void* d_out, int out_size, void* d_ws,
                              size_t ws_size, hipStream_t stream) {
  (void)in_sizes;
  (void)n_in;
  (void)out_size;
  const float* x = (const float*)d_in[0];
  const float* w1 = (const float*)d_in[1];
  const float* b1 = (const float*)d_in[2];
  const float* w2 = (const float*)d_in[3];
  const float* b2 = (const float*)d_in[4];
  const float* w3 = (const float*)d_in[5];
  const float* b3 = (const float*)d_in[6];
  const float* w_in = (const float*)d_in[7];
  const float* w_rec = (const float*)d_in[8];
  const float* w_fc = (const float*)d_in[9];
  const float* b_fc = (const float*)d_in[10];
  float* out = (float*)d_out;
  char* ws = (char*)d_ws;

  // ws: ff 1MB | P 8MB | w2p | w3p | winp | w1p | xh | xl | per-chunk bufs
  const size_t OFF_W2P = 1048576ull + 8388608ull;     // 9,437,184
  const size_t OFF_W3P = OFF_W2P + 147456ull;         // 9,584,640
  const size_t OFF_WIN = OFF_W3P + 221184ull;         // 9,805,824
  const size_t OFF_W1P = OFF_WIN + 7077888ull;        // 16,883,712
  const size_t OFF_XH = OFF_W1P + 8192ull;            // 16,891,904
  const size_t OFF_XL = OFF_XH + 16777216ull;         // 33,669,120
  const size_t HDR = OFF_XL + 16777216ull;            // 50,446,336
  const size_t PERF = 50176ull + 55296ull;            // 105,472
  int C = 32;
  for (int c = 2048; c >= 32; c >>= 1) {
    if (HDR + (size_t)c * PERF <= ws_size) { C = c; break; }
  }
  float* ffbuf = (float*)ws;
  float* P = (float*)(ws + 1048576ull);
  _Float16* w2p = (_Float16*)(ws + OFF_W2P);
  _Float16* w3p = (_Float16*)(ws + OFF_W3P);
  _Float16* winp = (_Float16*)(ws + OFF_WIN);
  _Float16* w1p = (_Float16*)(ws + OFF_W1P);
  _Float16* xh = (_Float16*)(ws + OFF_XH);
  _Float16* xl = (_Float16*)(ws + OFF_XL);
  _Float16* y2s = (_Float16*)(ws + HDR);
  _Float16* fh = (_Float16*)(ws + HDR + (size_t)C * 50176ull);
  _Float16* fl = fh + (size_t)C * 13824;

  xprep_k<<<8192, 256, 0, stream>>>(x, xh, xl);
  w1prep_k<<<4, 256, 0, stream>>>(w1, w1p);
  w2prep_k<<<72, 256, 0, stream>>>(w2, w2p);
  w3prep_k<<<216, 256, 0, stream>>>(w3, w3p);
  winprep_k<<<6912, 256, 0, stream>>>(w_in, winp);

  const int nChunks = 2048 / C;
  const int mbN = (C + 31) / 32;
  for (int ch = 0; ch < nChunks; ++ch) {
    const int f0 = ch * C;
    conv2f_mfma_k<<<dim3(7, C / 2), 448, 0, stream>>>(
        xh + (size_t)f0 * 4096, xl + (size_t)f0 * 4096, b1, w1p, w2p, b2, y2s);
    conv3_mfma_k<<<C, 320, 0, stream>>>(y2s, w3p, b3, fh, fl);
    ffgemm_k<<<dim3(mbN, 8), 256, 0, stream>>>(fh, fl, winp, P, f0, C);
  }
  ffreduce_k<<<1024, 256, 0, stream>>>(P, ffbuf);
  scan_k<<<32, 64, 0, stream>>>(ffbuf, w_rec, w_fc, b_fc, out);
}

// Round 22
// 569.249 us; speedup vs baseline: 1.0412x; 1.0160x over previous
//
#include <hip/hip_runtime.h>
#include <math.h>

typedef _Float16 half8 __attribute__((ext_vector_type(8)));
typedef _Float16 half4 __attribute__((ext_vector_type(4)));
typedef float f32x16 __attribute__((ext_vector_type(16)));

// ---------------------------------------------------------------------------
// prep_k: fused one-shot preprocessing (block-range dispatch).
//  [0,8192)        xprep  : split x into xh/xl f16 planes
//  [8192,15104)    winprep: pack w_in into ff-GEMM B-fragment order
//  [15104,15176)   w2prep : pack w2 into MFMA-fragment order
//  [15176,15392)   w3prep : pack w3 into conv3 fragment order
//  [15392,15396)   w1prep : pack w1 (K padded 25->32)
// All bodies byte-identical to the former standalone kernels.
// ---------------------------------------------------------------------------
__global__ __launch_bounds__(256) void prep_k(
    const float* __restrict__ x, const float* __restrict__ w1,
    const float* __restrict__ w2, const float* __restrict__ w3,
    const float* __restrict__ w_in, _Float16* __restrict__ xh,
    _Float16* __restrict__ xl, _Float16* __restrict__ w1p,
    _Float16* __restrict__ w2p, _Float16* __restrict__ w3p,
    _Float16* __restrict__ winp) {
  const int blk = blockIdx.x;
  const int tid = threadIdx.x;
  if (blk < 8192) {  // ---- xprep ----
    const int i = blk * 256 + tid;
    const float4 v = *(const float4*)(x + (size_t)i * 4);
    half4 h, l;
    const float vv[4] = {v.x, v.y, v.z, v.w};
#pragma unroll
    for (int e = 0; e < 4; ++e) {
      const _Float16 hh = (_Float16)vv[e];
      h[e] = hh;
      l[e] = (_Float16)((vv[e] - (float)hh) * 1024.0f);
    }
    *(half4*)(xh + (size_t)i * 4) = h;
    *(half4*)(xl + (size_t)i * 4) = l;
  } else if (blk < 15104) {  // ---- winprep ----
    const int i = (blk - 8192) * 256 + tid;
    const int ks = i >> 11;
    const int rem = i & 2047;
    const int nt = rem >> 9;
    const int g = (rem >> 8) & 1;
    const int n = (rem >> 3) & 31;
    const int e = rem & 7;
    const int h = nt * 32 + n;
    const int k = ks * 16 + g * 8 + e;
    const float v = w_in[(size_t)h * 13824 + k];
    const _Float16 hh = (_Float16)v;
    winp[i] = hh;
    winp[1769472 + i] = (_Float16)((v - (float)hh) * 1024.0f);
  } else if (blk < 15176) {  // ---- w2prep ----
    const int i = (blk - 15104) * 256 + tid;
    const int tap = i >> 11;
    const int r = i & 2047;
    const int b2k = r >> 8;
    const int nt = b2k >> 2, s = (b2k >> 1) & 1, g = b2k & 1;
    const int n = (r >> 3) & 31, e = r & 7;
    const int och = nt * 32 + n;
    const int ic = s * 16 + g * 8 + e;
    const float v = w2[och * 288 + ic * 9 + tap];
    const _Float16 h = (_Float16)v;
    w2p[i] = h;
    w2p[18432 + i] = (_Float16)((v - (float)h) * 1024.0f);
  } else if (blk < 15392) {  // ---- w3prep ----
    const int i = (blk - 15176) * 256 + tid;
    const int icc = i / 27648;
    const int r1 = i - icc * 27648;
    const int tc = r1 / 6144;
    const int rem = r1 - tc * 6144;
    const int tl = rem / 3072;
    const int rem2 = rem - tl * 3072;
    const int nt = rem2 >> 10;
    const int s = (rem2 >> 9) & 1;
    const int g = (rem2 >> 8) & 1;
    const int n = (rem2 >> 3) & 31;
    const int e = rem2 & 7;
    const int tap = tc * 2 + tl;
    const int och = nt * 32 + n;
    const int ic = icc * 32 + s * 16 + g * 8 + e;
    const float v = w3[(size_t)och * 576 + ic * 9 + tap];
    const _Float16 h = (_Float16)v;
    w3p[i] = h;
    w3p[55296 + i] = (_Float16)((v - (float)h) * 1024.0f);
  } else {  // ---- w1prep ----
    const int i = (blk - 15392) * 256 + tid;
    const int b1k = i >> 8;
    const int s = b1k >> 1, g = b1k & 1;
    const int ch = (i >> 3) & 31, e = i & 7;
    const int k = s * 16 + g * 8 + e;
    float v = 0.f;
    if (k < 25) v = w1[ch * 25 + k];
    const _Float16 h = (_Float16)v;
    w1p[i] = h;
    w1p[1024 + i] = (_Float16)((v - (float)h) * 1024.0f);
  }
}

// ---------------------------------------------------------------------------
// conv2f v7: FUSED conv1(MFMA) + conv2(MFMA) + maxpool (unchanged from R21).
// ---------------------------------------------------------------------------
__global__ __launch_bounds__(448) void conv2f_mfma_k(
    const _Float16* __restrict__ xh, const _Float16* __restrict__ xl,
    const float* __restrict__ b1, const _Float16* __restrict__ w1p,
    const _Float16* __restrict__ w2p, const float* __restrict__ b2,
    _Float16* __restrict__ y2s) {
  __shared__ __align__(16) _Float16 S[31232];
  const int rp = blockIdx.x;
  const int img0 = blockIdx.y * 2;
  const int tid = threadIdx.x;

  const int w = tid >> 6;
  const int lane = tid & 63;
  const int l31 = lane & 31;
  const int g = lane >> 5;

  // ---- phase 1 (x2 img-phases): conv1 via MFMA; 6 m-tiles of 32 ----
  {
    const float b1c = b1[l31];
    const int gb = l31 >> 3, e0 = l31 & 7;
    int xoffs[16];
#pragma unroll
    for (int s = 0; s < 2; ++s)
#pragma unroll
      for (int e = 0; e < 8; ++e) {
        const int k = s * 16 + g * 8 + e;
        const int ky = k / 5, kx = k - (k / 5) * 5;
        xoffs[s * 8 + e] = (k < 25) ? (ky * 64 + kx) : -1;
      }
#pragma unroll 1
    for (int ph = 0; ph < 2; ++ph) {
      if (tid < 240) {
        const int plane = tid / 120;
        const int c8 = tid - plane * 120;
        const _Float16* src = (plane ? xl : xh) +
                              (size_t)(img0 + ph) * 4096 + rp * 512 + c8 * 8;
        *(float4*)&S[23040 + plane * 960 + c8 * 8] = *(const float4*)src;
      }
      __syncthreads();
      if (w < 6) {
        const int p = w * 32 + l31;
        const int pcl = (p < 180) ? p : 179;
        const int row = pcl / 30;
        const int col = pcl - row * 30;
        const int xb = (2 * row) * 64 + 2 * col;
        f32x16 acc_h = {}, acc_l = {};
#pragma unroll
        for (int s = 0; s < 2; ++s) {
          half8 ah, al;
#pragma unroll
          for (int e = 0; e < 8; ++e) {
            const int o = xoffs[s * 8 + e];
            _Float16 hv = (_Float16)0.f, lv = (_Float16)0.f;
            if (o >= 0) {
              hv = S[23040 + xb + o];
              lv = S[24000 + xb + o];
            }
            ah[e] = hv;
            al[e] = lv;
          }
          const _Float16* bp = w1p + ((s * 2 + g) * 32 + l31) * 8;
          half8 bh = *(const half8*)bp;
          half8 bl = *(const half8*)(bp + 1024);
          acc_h = __builtin_amdgcn_mfma_f32_32x32x16_f16(ah, bh, acc_h, 0, 0, 0);
          acc_l = __builtin_amdgcn_mfma_f32_32x32x16_f16(ah, bl, acc_l, 0, 0, 0);
          acc_l = __builtin_amdgcn_mfma_f32_32x32x16_f16(al, bh, acc_l, 0, 0, 0);
        }
#pragma unroll
        for (int r = 0; r < 16; ++r) {
          const int mrow = (r & 3) + 8 * (r >> 2) + 4 * g;
          const int pp = w * 32 + mrow;
          if (pp < 180) {
            const int cl = pp - (pp / 30) * 30;
            const int swz = (cl >> 1) & 3;
            const int addr = ph * 5760 + pp * 32 + ((gb ^ swz) << 3) + e0;
            const float val =
                fmaxf(acc_h[r] + acc_l[r] * 9.765625e-4f + b1c, 0.f);
            const _Float16 hh = (_Float16)val;
            S[addr] = hh;
            S[11520 + addr] = (_Float16)((val - (float)hh) * 1024.0f);
          }
        }
      }
      __syncthreads();
    }
  }

  const int m = w * 32 + l31;
  const int aimg = m / 112;
  const int apos = m - aimg * 112;
  const int ar = apos / 28;
  const int ax = apos - ar * 28;
  const int icg = g * 8;

  f32x16 acc00 = {}, acc01 = {}, acc10 = {}, acc11 = {};

  // ---- phase 2: conv2 MFMA; A from LDS, B staged per-tc in LDS ----
#pragma unroll 1
  for (int tc = 0; tc < 5; ++tc) {
    __syncthreads();
    const int tap0 = tc * 2;
    const int ntaps = (tc == 4) ? 1 : 2;
    for (int c = tid; c < ntaps * 256; c += 448) {
      *(float4*)&S[23040 + c * 8] = *(const float4*)&w2p[tap0 * 2048 + c * 8];
      *(float4*)&S[27136 + c * 8] =
          *(const float4*)&w2p[18432 + tap0 * 2048 + c * 8];
    }
    __syncthreads();
#pragma unroll 1
    for (int tl = 0; tl < ntaps; ++tl) {
      const int tap = tap0 + tl;
      const int ky = tap / 3;
      const int kx = tap - ky * 3;
      const int acol = ax + kx;
      const int swzA = ((acol >> 1) & 3) << 3;
      const int abase = aimg * 5760 + ((ar + ky) * 30 + acol) * 32;
#pragma unroll
      for (int s = 0; s < 2; ++s) {
        const int icoA = (s * 16 + icg) ^ swzA;
        const int bo0 = 23040 + (((tl * 2 + 0) * 2 + s) * 2 + g) * 256 + l31 * 8;
        const int bo1 = 23040 + (((tl * 2 + 1) * 2 + s) * 2 + g) * 256 + l31 * 8;
        half8 ah = *(const half8*)&S[abase + icoA];
        half8 al = *(const half8*)&S[11520 + abase + icoA];
        half8 bh0 = *(const half8*)&S[bo0];
        half8 bl0 = *(const half8*)&S[bo0 + 4096];
        half8 bh1 = *(const half8*)&S[bo1];
        half8 bl1 = *(const half8*)&S[bo1 + 4096];
        acc00 = __builtin_amdgcn_mfma_f32_32x32x16_f16(ah, bh0, acc00, 0, 0, 0);
        acc10 = __builtin_amdgcn_mfma_f32_32x32x16_f16(ah, bl0, acc10, 0, 0, 0);
        acc10 = __builtin_amdgcn_mfma_f32_32x32x16_f16(al, bh0, acc10, 0, 0, 0);
        acc01 = __builtin_amdgcn_mfma_f32_32x32x16_f16(ah, bh1, acc01, 0, 0, 0);
        acc11 = __builtin_amdgcn_mfma_f32_32x32x16_f16(ah, bl1, acc11, 0, 0, 0);
        acc11 = __builtin_amdgcn_mfma_f32_32x32x16_f16(al, bh1, acc11, 0, 0, 0);
      }
    }
  }

  // ---- pool + bias + relu + split store, per-img halves ([112][68] f32) ----
  float* sPool = (float*)S;
#pragma unroll 1
  for (int ph = 0; ph < 2; ++ph) {
    __syncthreads();
#pragma unroll
    for (int r = 0; r < 16; ++r) {
      const int mrow = (r & 3) + 8 * (r >> 2) + 4 * g;
      const int mo = w * 32 + mrow;
      const int srow = mo - ph * 112;
      if (srow >= 0 && srow < 112) {
        sPool[srow * 68 + l31] = acc00[r] + acc10[r] * 9.765625e-4f;
        sPool[srow * 68 + 32 + l31] = acc01[r] + acc11[r] * 9.765625e-4f;
      }
    }
    __syncthreads();
    if (tid < 224) {
      const int pr = tid / 112;
      const int r2 = tid - pr * 112;
      const int pc = r2 >> 3;
      const int blk = r2 & 7;
      const int m00 = pr * 56 + pc * 2;
      const float* s0 = &sPool[m00 * 68 + blk * 8];
      float rowv[4][8];
      *(float4*)&rowv[0][0] = *(const float4*)s0;
      *(float4*)&rowv[0][4] = *(const float4*)(s0 + 4);
      *(float4*)&rowv[1][0] = *(const float4*)(s0 + 68);
      *(float4*)&rowv[1][4] = *(const float4*)(s0 + 72);
      *(float4*)&rowv[2][0] = *(const float4*)(s0 + 28 * 68);
      *(float4*)&rowv[2][4] = *(const float4*)(s0 + 28 * 68 + 4);
      *(float4*)&rowv[3][0] = *(const float4*)(s0 + 29 * 68);
      *(float4*)&rowv[3][4] = *(const float4*)(s0 + 29 * 68 + 4);
      half8 hv, lv;
#pragma unroll
      for (int e = 0; e < 8; ++e) {
        const float mx = fmaxf(fmaxf(rowv[0][e], rowv[1][e]),
                               fmaxf(rowv[2][e], rowv[3][e]));
        const float val = fmaxf(mx + b2[blk * 8 + e], 0.f);
        const _Float16 hh = (_Float16)val;
        hv[e] = hh;
        lv[e] = (_Float16)((val - (float)hh) * 1024.0f);
      }
      const int posg = (rp * 2 + pr) * 14 + pc;
      const int icc = blk >> 2;
      const int slot = (blk & 3) ^ ((posg >> 1) & 3);
      _Float16* dh = y2s + (size_t)(img0 + ph) * 25088 + icc * 6272 +
                     posg * 32 + slot * 8;
      *(float4*)dh = *(float4*)&hv;
      *(float4*)(dh + 12544) = *(float4*)&lv;
    }
  }
}

// ---------------------------------------------------------------------------
// conv3 v4: B-fragments direct from w3p (global); only X staged in LDS.
// ---------------------------------------------------------------------------
__global__ __launch_bounds__(320) void conv3_mfma_k(
    const _Float16* __restrict__ y2s, const _Float16* __restrict__ w3p,
    const float* __restrict__ b3, _Float16* __restrict__ fh,
    _Float16* __restrict__ fl) {
  __shared__ __align__(16) _Float16 S[12544];
  const int img = blockIdx.x;
  const int tid = threadIdx.x;
  const int w = tid >> 6;
  const int lane = tid & 63;
  const int l31 = lane & 31;
  const int g = lane >> 5;
  const int m = w * 32 + l31;
  const int mc = (m < 144) ? m : 143;
  const int r = mc / 12, c = mc - (mc / 12) * 12;

  f32x16 acch[3] = {};
  f32x16 accl[3] = {};

  const _Float16* bb = w3p + g * 256 + l31 * 8;
#pragma unroll 1
  for (int icc = 0; icc < 2; ++icc) {
    __syncthreads();
    {
      const _Float16* src = y2s + (size_t)img * 25088 + icc * 6272;
      for (int c8 = tid; c8 < 784; c8 += 320) {
        *(float4*)&S[c8 * 8] = *(const float4*)&src[c8 * 8];
        *(float4*)&S[6272 + c8 * 8] = *(const float4*)&src[12544 + c8 * 8];
      }
    }
    __syncthreads();
#pragma unroll 1
    for (int tc = 0; tc < 5; ++tc) {
      const int ntaps = (tc == 4) ? 1 : 2;
#pragma unroll 1
      for (int tl = 0; tl < ntaps; ++tl) {
        const int tap = tc * 2 + tl;
        const int ky = tap / 3, kx = tap - (tap / 3) * 3;
        const int pix = (r + ky) * 14 + (c + kx);
        const int pswz = (pix >> 1) & 3;
        half8 ah[2], al[2];
#pragma unroll
        for (int s = 0; s < 2; ++s) {
          const int o = pix * 32 + ((s * 2 + g) ^ pswz) * 8;
          ah[s] = *(const half8*)&S[o];
          al[s] = *(const half8*)&S[6272 + o];
        }
        const _Float16* bt = bb + icc * 27648 + tc * 6144 + tl * 3072;
#pragma unroll
        for (int nt = 0; nt < 3; ++nt) {
#pragma unroll
          for (int s = 0; s < 2; ++s) {
            const _Float16* bp = bt + nt * 1024 + s * 512;
            half8 bh = *(const half8*)bp;
            half8 bl = *(const half8*)(bp + 55296);
            acch[nt] =
                __builtin_amdgcn_mfma_f32_32x32x16_f16(ah[s], bh, acch[nt], 0, 0, 0);
            accl[nt] =
                __builtin_amdgcn_mfma_f32_32x32x16_f16(ah[s], bl, accl[nt], 0, 0, 0);
            accl[nt] =
                __builtin_amdgcn_mfma_f32_32x32x16_f16(al[s], bh, accl[nt], 0, 0, 0);
          }
        }
      }
    }
  }
  float* sO = (float*)S;
#pragma unroll
  for (int nt = 0; nt < 3; ++nt) {
    __syncthreads();
#pragma unroll
    for (int rr = 0; rr < 16; ++rr) {
      const int row = (rr & 3) + 8 * (rr >> 2) + 4 * g;
      const int pos = w * 32 + row;
      if (pos < 144)
        sO[l31 * 145 + pos] = acch[nt][rr] + accl[nt][rr] * 9.765625e-4f;
    }
    __syncthreads();
    for (int idx8 = tid; idx8 < 576; idx8 += 320) {
      const int oc = idx8 / 18;
      const int pb = idx8 - oc * 18;
      const float bb2 = b3[nt * 32 + oc];
      half8 hv, lv;
#pragma unroll
      for (int e = 0; e < 8; ++e) {
        const float v = fmaxf(sO[oc * 145 + pb * 8 + e] + bb2, 0.f);
        const _Float16 hh = (_Float16)v;
        hv[e] = hh;
        lv[e] = (_Float16)((v - (float)hh) * 1024.0f);
      }
      const size_t ko = (size_t)img * 13824 + (nt * 32 + oc) * 144 + pb * 8;
      *(float4*)&fh[ko] = *(float4*)&hv;
      *(float4*)&fl[ko] = *(float4*)&lv;
    }
  }
}

// ---------------------------------------------------------------------------
// ff GEMM via MFMA split-f16, BM=32 (unchanged from R21).
// ---------------------------------------------------------------------------
__global__ __launch_bounds__(256) void ffgemm_k(
    const _Float16* __restrict__ fh, const _Float16* __restrict__ fl,
    const _Float16* __restrict__ winp, float* __restrict__ P, int frame0,
    int Cl) {
  __shared__ __align__(16) _Float16 S[20480];
  const int mb = blockIdx.x;
  const int kc = blockIdx.y;
  const int tid = threadIdx.x;
  const int w = tid >> 6;
  const int lane = tid & 63;
  const int l31 = lane & 31;
  const int g = lane >> 5;
  f32x16 acc_h = {};
  f32x16 acc_l = {};
  const int kbase = kc * 1728;
#pragma unroll 1
  for (int kt = 0; kt < 27; ++kt) {
    __syncthreads();
    {
      const int row = tid >> 3, kb = tid & 7;
      int rc = mb * 32 + row;
      if (rc >= Cl) rc = Cl - 1;
      const size_t so = (size_t)rc * 13824 + kbase + kt * 64 + kb * 8;
      const int d = row * 64 + ((kb ^ (row & 7)) * 8);
      *(float4*)&S[d] = *(const float4*)&fh[so];
      *(float4*)&S[2048 + d] = *(const float4*)&fl[so];
    }
    {
      const size_t bo = (size_t)(kc * 108 + kt * 4) * 2048;
      for (int i = tid; i < 1024; i += 256) {
        *(float4*)&S[4096 + i * 8] = *(const float4*)&winp[bo + i * 8];
        *(float4*)&S[12288 + i * 8] =
            *(const float4*)&winp[1769472 + bo + i * 8];
      }
    }
    __syncthreads();
#pragma unroll
    for (int ks = 0; ks < 4; ++ks) {
      const int kb = ks * 2 + g;
      const int ao = l31 * 64 + ((kb ^ (l31 & 7)) * 8);
      half8 ah = *(const half8*)&S[ao];
      half8 al = *(const half8*)&S[2048 + ao];
      const int b = 4096 + (((ks * 4 + w) * 2 + g) * 32 + l31) * 8;
      half8 bh = *(const half8*)&S[b];
      half8 bl = *(const half8*)&S[b + 8192];
      acc_h = __builtin_amdgcn_mfma_f32_32x32x16_f16(ah, bh, acc_h, 0, 0, 0);
      acc_l = __builtin_amdgcn_mfma_f32_32x32x16_f16(ah, bl, acc_l, 0, 0, 0);
      acc_l = __builtin_amdgcn_mfma_f32_32x32x16_f16(al, bh, acc_l, 0, 0, 0);
    }
  }
  float* Pp = P + ((size_t)kc * 2048 + (size_t)frame0) * 128;
  const int h = w * 32 + l31;
#pragma unroll
  for (int r = 0; r < 16; ++r) {
    const int row = (r & 3) + 8 * (r >> 2) + 4 * g;
    const int fr = mb * 32 + row;
    if (fr < Cl) Pp[(size_t)fr * 128 + h] = acc_h[r] + acc_l[r] * 9.765625e-4f;
  }
}

__global__ __launch_bounds__(256) void ffreduce_k(const float* __restrict__ P,
                                                  float* __restrict__ ffo) {
  const int i = blockIdx.x * 256 + threadIdx.x;
  float s = 0.f;
#pragma unroll
  for (int kcc = 0; kcc < 8; ++kcc) s += P[(size_t)kcc * 262144 + i];
  ffo[i] = s;
}

// ---------------------------------------------------------------------------
// Recurrent LIF scan (unchanged)
// ---------------------------------------------------------------------------
__global__ __launch_bounds__(64) void scan_k(
    const float* __restrict__ ff, const float* __restrict__ w_rec,
    const float* __restrict__ w_fc, const float* __restrict__ b_fc,
    float* __restrict__ out) {
#pragma clang fp contract(off)
  __shared__ float sWr[16384];
  const int b = blockIdx.x;
  const int t = threadIdx.x;
  for (int idx = t; idx < 16384; idx += 64) {
    int hh = idx >> 7, j = idx & 127;
    sWr[j * 128 + hh] = w_rec[idx];
  }
  float wf0[10], wf1[10], bf[10];
#pragma unroll
  for (int c = 0; c < 10; ++c) {
    wf0[c] = w_fc[c * 128 + t];
    wf1[c] = w_fc[c * 128 + 64 + t];
    bf[c] = b_fc[c];
  }
  __syncthreads();
  float v0 = 0.f, v1 = 0.f, i0 = 0.f, i1 = 0.f;
  float vr[10], ir[10], vmax[10];
#pragma unroll
  for (int c = 0; c < 10; ++c) {
    vr[c] = 0.f;
    ir[c] = 0.f;
    vmax[c] = -1e30f;
  }
  unsigned long long pm0 = 0ull, pm1 = 0ull;
  const float* ffb = ff + (size_t)b * 8192;
#pragma unroll 1
  for (int ts = 0; ts < 64; ++ts) {
    const float vd0 = v0 + 0.1f * (i0 - v0);
    const float vd1 = v1 + 0.1f * (i1 - v1);
    const float id0 = i0 - 0.2f * i0;
    const float id1 = i1 - 0.2f * i1;
    const bool z0 = (vd0 - 0.4f) > 0.f;
    const bool z1 = (vd1 - 0.4f) > 0.f;
    v0 = z0 ? 0.f : vd0;
    v1 = z1 ? 0.f : vd1;
    float rec0 = 0.f, rec1 = 0.f;
    unsigned long long mm = pm0;
    while (mm) {
      int j = __ffsll(mm) - 1;
      mm &= mm - 1;
      rec0 += sWr[j * 128 + t];
      rec1 += sWr[j * 128 + t + 64];
    }
    mm = pm1;
    while (mm) {
      int j = __ffsll(mm) - 1;
      mm &= mm - 1;
      rec0 += sWr[(j + 64) * 128 + t];
      rec1 += sWr[(j + 64) * 128 + t + 64];
    }
    i0 = (id0 + ffb[ts * 128 + t]) + rec0;
    i1 = (id1 + ffb[ts * 128 + 64 + t]) + rec1;
    pm0 = __ballot(z0);
    pm1 = __ballot(z1);
#pragma unroll
    for (int c = 0; c < 10; ++c) {
      float val = (z0 ? wf0[c] : 0.f) + (z1 ? wf1[c] : 0.f);
      val += __shfl_xor(val, 1);
      val += __shfl_xor(val, 2);
      val += __shfl_xor(val, 4);
      val += __shfl_xor(val, 8);
      val += __shfl_xor(val, 16);
      val += __shfl_xor(val, 32);
      const float ro = val + bf[c];
      vr[c] = vr[c] + 0.1f * (ir[c] - vr[c]);
      vmax[c] = fmaxf(vmax[c], vr[c]);
      ir[c] = (ir[c] - 0.2f * ir[c]) + ro;
    }
  }
  if (t == 0) {
    float M = vmax[0];
#pragma unroll
    for (int c = 1; c < 10; ++c) M = fmaxf(M, vmax[c]);
    float s = 0.f;
#pragma unroll
    for (int c = 0; c < 10; ++c) s += expf(vmax[c] - M);
    const float ls = logf(s);
#pragma unroll
    for (int c = 0; c < 10; ++c) out[b * 10 + c] = vmax[c] - M - ls;
  }
}

// ---------------------------------------------------------------------------
extern "C" void kernel_launch(void* const* d_in, const int* in_sizes, int n_in,
                              void* d_out, int out_size, void* d_ws,
                              size_t ws_size, hipStream_t stream) {
  (void)in_sizes;
  (void)n_in;
  (void)out_size;
  const float* x = (const float*)d_in[0];
  const float* w1 = (const float*)d_in[1];
  const float* b1 = (const float*)d_in[2];
  const float* w2 = (const float*)d_in[3];
  const float* b2 = (const float*)d_in[4];
  const float* w3 = (const float*)d_in[5];
  const float* b3 = (const float*)d_in[6];
  const float* w_in = (const float*)d_in[7];
  const float* w_rec = (const float*)d_in[8];
  const float* w_fc = (const float*)d_in[9];
  const float* b_fc = (const float*)d_in[10];
  float* out = (float*)d_out;
  char* ws = (char*)d_ws;

  // ws: ff 1MB | P 8MB | w2p | w3p | winp | w1p | xh | xl | per-chunk bufs
  const size_t OFF_W2P = 1048576ull + 8388608ull;     // 9,437,184
  const size_t OFF_W3P = OFF_W2P + 147456ull;         // 9,584,640
  const size_t OFF_WIN = OFF_W3P + 221184ull;         // 9,805,824
  const size_t OFF_W1P = OFF_WIN + 7077888ull;        // 16,883,712
  const size_t OFF_XH = OFF_W1P + 8192ull;            // 16,891,904
  const size_t OFF_XL = OFF_XH + 16777216ull;         // 33,669,120
  const size_t HDR = OFF_XL + 16777216ull;            // 50,446,336
  const size_t PERF = 50176ull + 55296ull;            // 105,472
  int C = 32;
  for (int c = 2048; c >= 32; c >>= 1) {
    if (HDR + (size_t)c * PERF <= ws_size) { C = c; break; }
  }
  float* ffbuf = (float*)ws;
  float* P = (float*)(ws + 1048576ull);
  _Float16* w2p = (_Float16*)(ws + OFF_W2P);
  _Float16* w3p = (_Float16*)(ws + OFF_W3P);
  _Float16* winp = (_Float16*)(ws + OFF_WIN);
  _Float16* w1p = (_Float16*)(ws + OFF_W1P);
  _Float16* xh = (_Float16*)(ws + OFF_XH);
  _Float16* xl = (_Float16*)(ws + OFF_XL);
  _Float16* y2s = (_Float16*)(ws + HDR);
  _Float16* fh = (_Float16*)(ws + HDR + (size_t)C * 50176ull);
  _Float16* fl = fh + (size_t)C * 13824;

  prep_k<<<15396, 256, 0, stream>>>(x, w1, w2, w3, w_in, xh, xl, w1p, w2p,
                                    w3p, winp);

  const int nChunks = 2048 / C;
  const int mbN = (C + 31) / 32;
  for (int ch = 0; ch < nChunks; ++ch) {
    const int f0 = ch * C;
    conv2f_mfma_k<<<dim3(7, C / 2), 448, 0, stream>>>(
        xh + (size_t)f0 * 4096, xl + (size_t)f0 * 4096, b1, w1p, w2p, b2, y2s);
    conv3_mfma_k<<<C, 320, 0, stream>>>(y2s, w3p, b3, fh, fl);
    ffgemm_k<<<dim3(mbN, 8), 256, 0, stream>>>(fh, fl, winp, P, f0, C);
  }
  ffreduce_k<<<1024, 256, 0, stream>>>(P, ffbuf);
  scan_k<<<32, 64, 0, stream>>>(ffbuf, w_rec, w_fc, b_fc, out);
}